// Round 2
// baseline (1026.553 us; speedup 1.0000x reference)
//
#include <hip/hip_runtime.h>
#include <math.h>

// ---------------- problem constants ----------------
#define NLD 16      // degrees l = 0..15
#define NSX 136     // # (l, m>=0) pairs = sum(l+1)
#define NS  256     // # (l, m) pairs full = NL^2
#define KG  24      // kernel grid points
#define FI  64
#define FO  128
#define NB  8
#define NJI 64      // 2*B_IN
#define NJO 32      // 2*B_OUT
#define NZ  2856    // # (l, m>=0, n) triples = sum (l+1)(2l+1)
#define SCALING 0.07216878364870323  // 1/sqrt(24*64*16^3/32^3) = 1/sqrt(192)

// base offset of degree l in the (l,m>=0,n) l-major packing
__device__ const int BASE[17] = {0,1,7,22,50,95,161,252,372,525,715,946,
                                 1222,1547,1925,2360,2856};

__device__ const double FACT[33] = {
  1.0,1.0,2.0,6.0,24.0,120.0,720.0,5040.0,40320.0,362880.0,3628800.0,
  39916800.0,479001600.0,6227020800.0,87178291200.0,1307674368000.0,
  20922789888000.0,355687428096000.0,6402373705728000.0,121645100408832000.0,
  2432902008176640000.0,51090942171709440000.0,1124000727777607680000.0,
  25852016738884976640000.0,620448401733239439360000.0,
  15511210043330985984000000.0,403291461126605635584000000.0,
  10888869450418352160768000000.0,304888344611713860501504000000.0,
  8841761993739701954543616000000.0,265252859812191058636308480000000.0,
  8222838654177922817725562880000000.0,263130836933693530167218012160000000.0};

// Wigner small-d d^l_{m,n}(beta), double precision, matches reference formula
__device__ double wig_d(int l, int m, int n, double beta) {
  double cb = cos(0.5 * beta), sb = sin(0.5 * beta);
  int smin = max(0, n - m), smax = min(l + n, l - m);
  double pref = sqrt(FACT[l + m] * FACT[l - m] * FACT[l + n] * FACT[l - n]);
  int ec = 2 * l + n - m - 2 * smin;   // >= 0
  int es = m - n + 2 * smin;           // >= 0
  double p = 1.0;
  for (int t = 0; t < ec; ++t) p *= cb;
  for (int t = 0; t < es; ++t) p *= sb;
  double r = (sb * sb) / (cb * cb);
  double out = 0.0;
  for (int s = smin; s <= smax; ++s) {
    double coef = 1.0 / (FACT[l + n - s] * FACT[s] * FACT[m - n + s] * FACT[l - m - s]);
    if ((m - n + s) & 1) coef = -coef;
    out += coef * p;
    p *= r;
  }
  return pref * out;
}

// ---------------- K0: all transform constants (fp64 -> fp32) ----------------
// WD [NSX][NJI]  : beta-quadrature-weighted d^l_{m,0}(beta_j) * (2pi/64)
// YK [NS][KG]    : SCALING * d^l_{m,0}(gb_k) * e^{-i m ga_k}
// Dp [NJO][NZ]   : (2l+1) * d^l_{m,n}(beta'_j),  l-major (l, m>=0, n) packing
__global__ __launch_bounds__(256) void k_const(float* __restrict__ WD,
                                               float2* __restrict__ YK,
                                               float* __restrict__ Dp) {
  int idx = blockIdx.x * 256 + threadIdx.x;
  if (idx < NSX * NJI) {
    int sx = idx / NJI, j = idx % NJI;
    int l = 0; while ((l + 1) * (l + 2) / 2 <= sx) ++l;
    int m = sx - l * (l + 1) / 2;
    double beta = (j + 0.5) * M_PI / NJI;
    double s = 0.0;
    for (int k = 0; k < 32; ++k)
      s += sin((2.0 * j + 1.0) * (2.0 * k + 1.0) * M_PI / 128.0) / (2.0 * k + 1.0);
    double w = (2.0 / 32.0) * sin(beta) * s * (2.0 * M_PI / 64.0);
    WD[sx * NJI + j] = (float)(w * wig_d(l, m, 0, beta));
    return;
  }
  idx -= NSX * NJI;
  if (idx < NS * KG) {
    int sidx = idx / KG, k = idx % KG;
    int l = 0; while ((l + 1) * (l + 1) <= sidx) ++l;
    int m = sidx - l * l - l;                       // signed m
    double gb = (double)(k / 8 + 1) * (M_PI / 8.0) / 3.0;
    double ga = (double)(k % 8) * (2.0 * M_PI / 8.0);
    double d = wig_d(l, m, 0, gb) * SCALING;
    double sn, c; sincos((double)m * ga, &sn, &c);
    YK[sidx * KG + k] = make_float2((float)(d * c), (float)(-d * sn)); // e^{-i m a}
    return;
  }
  idx -= NS * KG;
  if (idx < NJO * NZ) {
    int j = idx / NZ, z = idx % NZ;
    int l = 0; while (BASE[l + 1] <= z) ++l;
    int rem = z - BASE[l];
    int m = rem / (2 * l + 1);
    int n = rem % (2 * l + 1) - l;                  // signed n
    double beta = (j + 0.5) * M_PI / NJO;
    Dp[j * NZ + z] = (float)((2 * l + 1) * wig_d(l, m, n, beta));
  }
}

// ---------------- K1: S2 forward transform ----------------
// one block per (b, f): 64-pt DFT over alpha (bins m=0..15 only), then
// beta-quadrature contraction -> X[(l*16+m)][b][f] (zero-padded for m>l)
__global__ __launch_bounds__(256) void k_s2fft(const float* __restrict__ x,
                                               const float* __restrict__ WD,
                                               float2* __restrict__ X) {
  __shared__ float  xl[NJI * NJI];   // [j][a] 16 KB
  __shared__ float2 tw[NJI];
  __shared__ float2 xf[NJI * 16];    // [j][m] 8 KB
  __shared__ float2 fx[NSX];
  int t = threadIdx.x;
  int b = blockIdx.x >> 6, f = blockIdx.x & 63;
  const float* xp = x + (size_t)(b * FI + f) * (NJI * NJI);
  for (int r = 0; r < 16; ++r) xl[t + 256 * r] = xp[t + 256 * r];
  if (t < NJI) {
    double s_, c_; sincos(2.0 * M_PI * t / NJI, &s_, &c_);
    tw[t] = make_float2((float)c_, (float)s_);
  }
  __syncthreads();
  for (int r = 0; r < 4; ++r) {
    int oi = t + 256 * r;            // oi = j*16 + m
    int j = oi >> 4, m = oi & 15;
    float re = 0.f, im = 0.f;
    const float* row = xl + j * NJI;
    for (int a = 0; a < NJI; ++a) {
      float2 w = tw[(m * a) & 63];
      float v = row[a];
      re += v * w.x; im -= v * w.y;  // e^{-2pi i m a / 64}
    }
    xf[oi] = make_float2(re, im);
  }
  __syncthreads();
  if (t < NSX) {
    int l = 0; while ((l + 1) * (l + 2) / 2 <= t) ++l;
    int m = t - l * (l + 1) / 2;
    float re = 0.f, im = 0.f;
    const float* wrow = WD + t * NJI;
    for (int j = 0; j < NJI; ++j) {
      float wv = wrow[j];
      float2 v = xf[j * 16 + m];
      re += wv * v.x; im += wv * v.y;
    }
    fx[t] = make_float2(re, im);
  }
  __syncthreads();
  {
    int l = t >> 4, m = t & 15;
    float2 v = make_float2(0.f, 0.f);
    if (m <= l) v = fx[l * (l + 1) / 2 + m];
    X[((size_t)t * NB + b) * FI + f] = v;           // row t = l*16+m (padded)
  }
}

// ---------------- K2: kernel spherical transform ----------------
// Y[s][i][o] = sum_k kernel[i][o][k] * YK[s][k]   (all 256 s)
__global__ __launch_bounds__(256) void k_ytrans(const float* __restrict__ kern,
                                                const float2* __restrict__ YK,
                                                float2* __restrict__ Y) {
  __shared__ float  kl[FO][KG + 1];
  __shared__ float2 ykl[32][KG];
  int t = threadIdx.x;
  int i = blockIdx.x & 63, st = blockIdx.x >> 6;   // s-tile of 32
  int s0 = st * 32;
  for (int r = 0; r < 12; ++r) {
    int fid = t + 256 * r;                          // 3072 floats
    kl[fid / KG][fid % KG] = kern[(size_t)i * FO * KG + fid];
  }
  for (int r = 0; r < 3; ++r) {
    int fid = t + 256 * r;                          // 768 float2
    ykl[fid / KG][fid % KG] = YK[(s0 + fid / KG) * KG + fid % KG];
  }
  __syncthreads();
  int o = t & 127, sh = t >> 7;
  float kr[KG];
  #pragma unroll
  for (int k = 0; k < KG; ++k) kr[k] = kl[o][k];
  for (int ss = sh; ss < 32; ss += 2) {
    float re = 0.f, im = 0.f;
    #pragma unroll
    for (int k = 0; k < KG; ++k) {
      float2 yv = ykl[ss][k];
      re += kr[k] * yv.x; im += kr[k] * yv.y;
    }
    Y[((size_t)(s0 + ss) * FI + i) * FO + o] = make_float2(re, im);
  }
}

// ---------------- K3: block-diagonal spectral matmul ----------------
// Z[b][o][zidx] = sum_i X[l,m,b,i] * conj(Y[l,n,i,o]),  m>=0 triples only.
// m padded to 16 (X rows m>l are zero) for branchless register accumulation.
__global__ __launch_bounds__(256) void k_zmm(const float2* __restrict__ X,
                                             const float2* __restrict__ Y,
                                             float2* __restrict__ Z) {
  __shared__ float2 xs[256 * 16];    // [row=l*16+m][ii] 32 KB
  int t = threadIdx.x;
  int b  = blockIdx.x >> 6;
  int ot = (blockIdx.x >> 4) & 3;
  int st = blockIdx.x & 15;          // s-tile of 16
  int s0 = st * 16;
  int o  = ot * 32 + (t & 31);
  int sg = t >> 5;                   // 0..7
  int sq[2] = { s0 + sg, s0 + sg + 8 };
  int lq[2], nq[2];
  #pragma unroll
  for (int q = 0; q < 2; ++q) {
    int s = sq[q];
    int l = 0; while ((l + 1) * (l + 1) <= s) ++l;
    lq[q] = l; nq[q] = s - l * l;    // = n + l
  }
  float2 acc[2][16];
  #pragma unroll
  for (int q = 0; q < 2; ++q)
    #pragma unroll
    for (int m = 0; m < 16; ++m) acc[q][m] = make_float2(0.f, 0.f);

  for (int ic = 0; ic < 4; ++ic) {
    __syncthreads();
    for (int r = 0; r < 16; ++r) {
      int fid = t + 256 * r;         // 4096 float2
      int row = fid >> 4, ii = fid & 15;
      xs[fid] = X[((size_t)row * NB + b) * FI + ic * 16 + ii];
    }
    __syncthreads();
    for (int ii = 0; ii < 16; ++ii) {
      int i = ic * 16 + ii;
      #pragma unroll
      for (int q = 0; q < 2; ++q) {
        float2 yv = Y[((size_t)sq[q] * FI + i) * FO + o];
        const float2* xrow = xs + (lq[q] * 16) * 16 + ii;
        #pragma unroll
        for (int m = 0; m < 16; ++m) {
          float2 xv = xrow[m * 16];
          acc[q][m].x += xv.x * yv.x + xv.y * yv.y;   // X * conj(Y)
          acc[q][m].y += xv.y * yv.x - xv.x * yv.y;
        }
      }
    }
  }
  size_t zb = ((size_t)b * FO + o) * NZ;
  for (int q = 0; q < 2; ++q) {
    int l = lq[q];
    for (int m = 0; m <= l; ++m) {
      int zidx = BASE[l] + m * (2 * l + 1) + nq[q];
      Z[zb + zidx] = acc[q][m];
    }
  }
}

// ---------------- K4: SO(3) synthesis ----------------
// one block per (b,o); Z slice staged to LDS once (single __syncthreads).
// Each wave owns j = jj*4 + wave with private LDS T/U scratch:
//   T[m,n] = sum_l Dp[j][zidx]*Z[zidx]          (m=0..15, n=-15..15)
//   U[m,g] = sum_n T[m,n] e^{+2pi i n g/32}
//   f[a,g] = Re U[0,g] + 2 sum_{m>=1} (cos(2pi m a/32) ReU - sin ImU)
// (negative m folded via Hermitian symmetry U[-m,g] = conj U[m,g])
__global__ __launch_bounds__(256) void k_synth(const float2* __restrict__ Z,
                                               const float* __restrict__ Dp,
                                               float* __restrict__ out) {
  __shared__ float2 zs[NZ];          // 22.8 KB
  __shared__ float2 tt[4][496];      // per-wave T  (16 x 31)
  __shared__ float2 uu[4][512];      // per-wave U  (16 x 32)
  __shared__ float2 tws[32];
  int t = threadIdx.x;
  int b = blockIdx.x >> 7, o = blockIdx.x & 127;
  const float2* zg = Z + ((size_t)b * FO + o) * NZ;
  for (int r = 0; r < 12; ++r) {
    int fid = t + 256 * r;
    if (fid < NZ) zs[fid] = zg[fid];
  }
  if (t < 32) {
    double s_, c_; sincos(2.0 * M_PI * t / 32.0, &s_, &c_);
    tws[t] = make_float2((float)c_, (float)s_);
  }
  __syncthreads();                   // the only block-wide barrier
  int w = t >> 6, lane = t & 63;
  float* outb = out + ((size_t)b * FO + o) * (NJO * NJO * NJO);
  for (int jj = 0; jj < 8; ++jj) {
    int j = jj * 4 + w;
    const float* dpj = Dp + (size_t)j * NZ;
    // ---- T ----
    for (int k = 0; k < 8; ++k) {
      int p = lane + 64 * k;
      if (p < 496) {
        int m = p / 31, nn = p % 31;
        int n = nn - 15;
        int an = n < 0 ? -n : n;
        int lmin = m > an ? m : an;
        float re = 0.f, im = 0.f;
        for (int l = lmin; l < 16; ++l) {
          int idx = BASE[l] + m * (2 * l + 1) + (n + l);
          float d = dpj[idx];
          float2 zv = zs[idx];
          re += d * zv.x; im += d * zv.y;
        }
        tt[w][p] = make_float2(re, im);
      }
    }
    // ---- U ---- (same-wave LDS producer/consumer; DS ops are in-order per wave)
    for (int k = 0; k < 8; ++k) {
      int oi = lane + 64 * k;        // oi = m*32 + g
      int m = oi >> 5, g = oi & 31;
      float ur = 0.f, ui = 0.f;
      int idx = (17 * g) & 31;       // (-15*g) mod 32
      const float2* trow = tt[w] + m * 31;
      #pragma unroll
      for (int n = 0; n < 31; ++n) {
        float2 tv = trow[n];
        float2 wv = tws[idx];
        ur += tv.x * wv.x - tv.y * wv.y;
        ui += tv.x * wv.y + tv.y * wv.x;
        idx = (idx + g) & 31;
      }
      uu[w][oi] = make_float2(ur, ui);
    }
    // ---- f ----
    float* outj = outb + (size_t)j * 1024;
    for (int k = 0; k < 16; ++k) {
      int oi = lane + 64 * k;        // oi = a*32 + g
      int a = oi >> 5, g = oi & 31;
      float val = uu[w][g].x;        // m = 0 term
      #pragma unroll
      for (int m = 1; m < 16; ++m) {
        float2 wv = tws[(m * a) & 31];
        float2 um = uu[w][m * 32 + g];
        val += 2.f * (wv.x * um.x - wv.y * um.y);
      }
      outj[oi] = val;
    }
  }
}

// ---------------- launch ----------------
extern "C" void kernel_launch(void* const* d_in, const int* in_sizes, int n_in,
                              void* d_out, int out_size, void* d_ws, size_t ws_size,
                              hipStream_t stream) {
  (void)in_sizes; (void)n_in; (void)out_size; (void)ws_size;
  const float* x    = (const float*)d_in[0];
  const float* kern = (const float*)d_in[1];
  float* out = (float*)d_out;
  float* ws  = (float*)d_ws;
  // workspace layout (float offsets, all 8B-aligned)
  float*  WD = ws;                        // 8704 f
  float2* YK = (float2*)(ws + 8704);      // 6144 f2
  float*  Dp = ws + 20992;                // 91392 f
  float2* X  = (float2*)(ws + 112384);    // 131072 f2
  float2* Y  = (float2*)(ws + 374528);    // 2097152 f2
  float2* Z  = (float2*)(ws + 4568832);   // 2924544 f2  (ends at 41.7 MB)
  hipLaunchKernelGGL(k_const,  dim3(416),  dim3(256), 0, stream, WD, YK, Dp);
  hipLaunchKernelGGL(k_s2fft,  dim3(512),  dim3(256), 0, stream, x, WD, X);
  hipLaunchKernelGGL(k_ytrans, dim3(512),  dim3(256), 0, stream, kern, YK, Y);
  hipLaunchKernelGGL(k_zmm,    dim3(512),  dim3(256), 0, stream, X, Y, Z);
  hipLaunchKernelGGL(k_synth,  dim3(1024), dim3(256), 0, stream, Z, Dp, out);
}